// Round 12
// baseline (266.789 us; speedup 1.0000x reference)
//
#include <hip/hip_runtime.h>
#include <hip/hip_bf16.h>

// GATNet 2-layer GAT, N=50000, E=800000 (+N self loops). f32 in/out, bf16 MFMA.
// Round-12: launch-count 9->6 with grid-partitioned fusion:
//   k_gz            : init bucket cursors + done flag (tiny)
//   k_initbucket    : blocks 0-63 = weight pack; rest = edge bucketing;
//                     last bucket block runs the bucket-scan inline (done-ctr)
//   k_fillgemm0     : blocks 0-195 = per-bucket CSR fill; rest = gemm0
//   k_agg0 / k_gemm1 / k_agg1
// agg kernels deepened to 4 edges in flight per 16-lane group (more MLP).

typedef __attribute__((ext_vector_type(8))) short bf8_t;   // 8 x bf16 (4 VGPRs)
typedef __attribute__((ext_vector_type(4))) float f4_t;

#define NBUCK 256      // bucket table size (used buckets = (N+255)>>8 = 196)
#define BCAP  8192     // per-bucket capacity (expected ~4352, uniform random)

__device__ inline short f2bf(float f) {
    return (short)__builtin_bit_cast(unsigned short, __float2bfloat16(f));
}
__device__ inline float blo(unsigned int p) { return __uint_as_float(p << 16); }
__device__ inline float bhi(unsigned int p) { return __uint_as_float(p & 0xffff0000u); }
__device__ inline float lrexp(float e) {
    e = (e > 0.f) ? e : 0.2f * e;          // leaky_relu(0.2); |e|<~12 -> exp safe
    return __expf(e);
}

// ---------------- tiny init: bucket cursors + done flag ----------------
__global__ void k_gz(int* __restrict__ gcur, int* __restrict__ done) {
    int i = threadIdx.x;
    gcur[i] = i * BCAP;
    if (i == 0) *done = 0;
}

// ---- fused: weight pack (blocks 0..63)  |  edge bucketing (blocks 64..) ----
// Wp[((ct*4+kb)*64 + lane)*8 + j] = W[ct*16 + (lane&15)][kb*32 + (lane>>4)*8 + j]
__global__ __launch_bounds__(256) void k_initbucket(
    const int* __restrict__ ei,
    const float* __restrict__ W0, const float* __restrict__ lW0,
    const float* __restrict__ W1, const float* __restrict__ lW1,
    const float* __restrict__ b0, const float* __restrict__ lb0,
    const float* __restrict__ b1, const float* __restrict__ lb1,
    short* __restrict__ Wp0, short* __restrict__ lWp0,
    short* __restrict__ Wp1, short* __restrict__ lWp1,
    float* __restrict__ bc0, float* __restrict__ bc1,
    int* __restrict__ gcur, int* __restrict__ done,
    int* __restrict__ bbase, int* __restrict__ rowstart,
    unsigned int* __restrict__ bucketed, int E, int T, int N) {
    __shared__ int hist[NBUCK];
    __shared__ int gbase[NBUCK];
    __shared__ int lastflag;
    int tid = threadIdx.x;

    if (blockIdx.x < 64) {                 // ---- weight/bias pack ----
        int i = blockIdx.x * 256 + tid;    // 0..16383
        {
            int j = i & 7, lane = (i >> 3) & 63, kc = i >> 9;
            int kb = kc & 3, ct = kc >> 2;
            int src = (ct * 16 + (lane & 15)) * 128 + kb * 32 + (lane >> 4) * 8 + j;
            Wp0[i]  = f2bf(W0[src]);
            lWp0[i] = f2bf(lW0[src]);
            if (i < 4096) {
                Wp1[i]  = f2bf(W1[src]);
                lWp1[i] = f2bf(lW1[src]);
            }
        }
        if (i < 128) bc0[i] = b0[i] + lb0[i];
        else if (i < 160) bc1[i - 128] = b1[i - 128] + lb1[i - 128];
        return;
    }

    // ---- bucketing: 2048 edges/block, LDS-ranked runs ----
    int bb = blockIdx.x - 64;
    hist[tid] = 0;
    __syncthreads();
    int base = bb * 2048;
    unsigned int pk[8]; int rk[8]; int bk[8];
    #pragma unroll
    for (int j = 0; j < 8; j++) {
        int e = base + j * 256 + tid;
        if (e < T) {
            int src, dst;
            if (e < E) { src = ei[e]; dst = ei[E + e]; }
            else       { src = e - E; dst = src; }          // self-loops
            int b = dst >> 8;
            pk[j] = ((unsigned int)dst << 16) | (unsigned int)src;
            bk[j] = b;
            rk[j] = atomicAdd(&hist[b], 1);
        } else bk[j] = -1;
    }
    __syncthreads();
    int h = hist[tid];
    if (h > 0) gbase[tid] = atomicAdd(&gcur[tid], h);
    __syncthreads();
    #pragma unroll
    for (int j = 0; j < 8; j++)
        if (bk[j] >= 0)
            bucketed[gbase[bk[j]] + rk[j]] = pk[j];

    // last bucket block runs the 256-entry bucket scan inline
    __threadfence();
    __syncthreads();
    if (tid == 0) lastflag = (atomicAdd(done, 1) == (int)(gridDim.x - 64) - 1);
    __syncthreads();
    if (!lastflag) return;
    int v = atomicAdd(&gcur[tid], 0) - tid * BCAP;   // coherent read
    hist[tid] = v;
    __syncthreads();
    for (int off = 1; off < NBUCK; off <<= 1) {
        int tv = (tid >= off) ? hist[tid - off] : 0;
        __syncthreads();
        hist[tid] += tv;
        __syncthreads();
    }
    bbase[tid] = hist[tid] - v;            // exclusive
    if (tid == NBUCK - 1) rowstart[N] = hist[tid];
}

// ---------------- fused: CSR fill (blocks 0..NBK-1) | GEMM0 (rest) ----------
// fill: one block per bucket; LDS histogram+scan -> rowstart slice + esrc fill.
// gemm0: A-frag lane=A[m=lane&15][k=(lane>>4)*8+j]; B from packed tables;
// C/D col=lane&15,row=(lane>>4)*4+reg (m89-verified); LDS-staged coalesced out.

#define TSTR 136   // LDS tile row stride in shorts (272B, 16B-aligned)

__global__ __launch_bounds__(256) void k_fillgemm0(
    const unsigned int* __restrict__ bucketed, const int* __restrict__ gcur,
    const int* __restrict__ bbase, int* __restrict__ rowstart,
    unsigned short* __restrict__ esrc,
    const float* __restrict__ x,
    const short* __restrict__ Wp0, const short* __restrict__ lWp0,
    const float* __restrict__ as0, const float* __restrict__ ad0,
    __hip_bfloat16* __restrict__ h0, __hip_bfloat16* __restrict__ skipb,
    float* __restrict__ a0s, float* __restrict__ a0d, int N) {
    __shared__ int ihist[256];
    __shared__ int incl[256];
    __shared__ short tile[4][16 * TSTR];
    int NBK = (N + 255) >> 8;

    if ((int)blockIdx.x < NBK) {           // ---- CSR fill ----
        int b = blockIdx.x, t = threadIdx.x;
        int nodebase = b << 8;
        int used = gcur[b] - b * BCAP;
        const unsigned int* bk = bucketed + (size_t)b * BCAP;
        ihist[t] = 0;
        __syncthreads();
        for (int i = t; i < used; i += 256)
            atomicAdd(&ihist[(bk[i] >> 16) - nodebase], 1);
        __syncthreads();
        int v = ihist[t];
        incl[t] = v;
        __syncthreads();
        for (int off = 1; off < 256; off <<= 1) {
            int tv = (t >= off) ? incl[t - off] : 0;
            __syncthreads();
            incl[t] += tv;
            __syncthreads();
        }
        int myexcl = incl[t] - v;
        int rbase = bbase[b];
        int node = nodebase + t;
        if (node < N) rowstart[node] = rbase + myexcl;
        __syncthreads();
        ihist[t] = myexcl;                 // reuse as fill cursor
        __syncthreads();
        for (int i = t; i < used; i += 256) {
            unsigned int p = bk[i];
            int pos = atomicAdd(&ihist[(p >> 16) - nodebase], 1);
            esrc[rbase + pos] = (unsigned short)(p & 0xffffu);
        }
        return;
    }

    // ---- GEMM0 + fused att0 ----
    int bx = blockIdx.x - NBK;
    int wv = threadIdx.x >> 6, lane = threadIdx.x & 63;
    int rowbase = bx * 64 + wv * 16;
    int m = lane & 15, q = lane >> 4;
    int arow = rowbase + m; if (arow >= N) arow = N - 1;
    bf8_t a[4];
    #pragma unroll
    for (int kb = 0; kb < 4; kb++) {
        const float4* px = (const float4*)(x + (size_t)arow * 128 + kb * 32 + q * 8);
        float4 lo = px[0], hi = px[1];
        bf8_t f;
        f[0] = f2bf(lo.x); f[1] = f2bf(lo.y); f[2] = f2bf(lo.z); f[3] = f2bf(lo.w);
        f[4] = f2bf(hi.x); f[5] = f2bf(hi.y); f[6] = f2bf(hi.z); f[7] = f2bf(hi.w);
        a[kb] = f;
    }
    float sacc[4][4], dacc[4][4];
    #pragma unroll
    for (int h = 0; h < 4; h++)
        #pragma unroll
        for (int r = 0; r < 4; r++) { sacc[h][r] = 0.f; dacc[h][r] = 0.f; }
    short* tl = tile[wv];
    int r4 = lane >> 2, qt = lane & 3;     // drain mapping: row, 64B quarter
    int drow = rowbase + r4;

    // phase 1: h0 (cts 0..7) + att accumulation
    #pragma unroll
    for (int ct = 0; ct < 8; ct++) {
        f4_t acc = {0.f, 0.f, 0.f, 0.f};
        #pragma unroll
        for (int kb = 0; kb < 4; kb++) {
            bf8_t b = *(const bf8_t*)(Wp0 + (((ct * 4 + kb) * 64 + lane) << 3));
            acc = __builtin_amdgcn_mfma_f32_16x16x32_bf16(a[kb], b, acc, 0, 0, 0);
        }
        int hd = ct >> 1;
        float ws = as0[ct * 16 + m], wd = ad0[ct * 16 + m];
        #pragma unroll
        for (int r = 0; r < 4; r++) {
            sacc[hd][r] += acc[r] * ws;
            dacc[hd][r] += acc[r] * wd;
            tl[(q * 4 + r) * TSTR + ct * 16 + m] = f2bf(acc[r]);
        }
    }
    if (drow < N) {
        short* dst = (short*)h0 + (size_t)drow * 128 + qt * 32;
        const short* srcp = tl + r4 * TSTR + qt * 32;
        #pragma unroll
        for (int s = 0; s < 4; s++)
            *(uint4*)(dst + s * 8) = *(const uint4*)(srcp + s * 8);
    }

    // phase 2: skip (cts 8..15) -> same tile, drain to skipb
    #pragma unroll
    for (int ct = 0; ct < 8; ct++) {
        f4_t acc = {0.f, 0.f, 0.f, 0.f};
        #pragma unroll
        for (int kb = 0; kb < 4; kb++) {
            bf8_t b = *(const bf8_t*)(lWp0 + (((ct * 4 + kb) * 64 + lane) << 3));
            acc = __builtin_amdgcn_mfma_f32_16x16x32_bf16(a[kb], b, acc, 0, 0, 0);
        }
        #pragma unroll
        for (int r = 0; r < 4; r++)
            tl[(q * 4 + r) * TSTR + ct * 16 + m] = f2bf(acc[r]);
    }
    if (drow < N) {
        short* dst = (short*)skipb + (size_t)drow * 128 + qt * 32;
        const short* srcp = tl + r4 * TSTR + qt * 32;
        #pragma unroll
        for (int s = 0; s < 4; s++)
            *(uint4*)(dst + s * 8) = *(const uint4*)(srcp + s * 8);
    }

    // att logits: reduce over the 16 m-lanes
    #pragma unroll
    for (int h = 0; h < 4; h++)
        #pragma unroll
        for (int r = 0; r < 4; r++) {
            float s = sacc[h][r], d = dacc[h][r];
            #pragma unroll
            for (int off = 1; off < 16; off <<= 1) {
                s += __shfl_xor(s, off);
                d += __shfl_xor(d, off);
            }
            sacc[h][r] = s; dacc[h][r] = d;
        }
    if (m < 4) {
        #pragma unroll
        for (int r = 0; r < 4; r++) {
            int row = rowbase + q * 4 + r;
            if (row < N) {
                float sv = (m == 0) ? sacc[0][r] : (m == 1) ? sacc[1][r]
                         : (m == 2) ? sacc[2][r] : sacc[3][r];
                float dv = (m == 0) ? dacc[0][r] : (m == 1) ? dacc[1][r]
                         : (m == 2) ? dacc[2][r] : dacc[3][r];
                a0s[row * 4 + m] = sv;
                a0d[row * 4 + m] = dv;
            }
        }
    }
}

// ---------------- GEMM1 + fused att1 ----------------

__global__ __launch_bounds__(256) void k_gemm1(
    const __hip_bfloat16* __restrict__ hin,
    const short* __restrict__ Wp1, const short* __restrict__ lWp1,
    const float* __restrict__ as1, const float* __restrict__ ad1,
    __hip_bfloat16* __restrict__ h1, float* __restrict__ skipb /* = d_out */,
    float* __restrict__ a1s, float* __restrict__ a1d, int N) {
    __shared__ short th[4][16 * 40];           // h1 tile (stride 40 shorts)
    __shared__ float ts[4][16 * 36];           // skip tile (stride 36 floats)
    int wv = threadIdx.x >> 6, lane = threadIdx.x & 63;
    int rowbase = blockIdx.x * 64 + wv * 16;
    int m = lane & 15, q = lane >> 4;
    int arow = rowbase + m; if (arow >= N) arow = N - 1;
    const short* xs = (const short*)hin;
    bf8_t a[4];
    #pragma unroll
    for (int kb = 0; kb < 4; kb++)
        a[kb] = *(const bf8_t*)(xs + (size_t)arow * 128 + kb * 32 + q * 8);
    float sacc[4], dacc[4];
    #pragma unroll
    for (int r = 0; r < 4; r++) { sacc[r] = 0.f; dacc[r] = 0.f; }
    short* tlh = th[wv];
    float* tls = ts[wv];
    int r4 = lane >> 2, qt = lane & 3;
    int drow = rowbase + r4;

    #pragma unroll
    for (int ct = 0; ct < 2; ct++) {           // h1 + att
        f4_t acc = {0.f, 0.f, 0.f, 0.f};
        #pragma unroll
        for (int kb = 0; kb < 4; kb++) {
            bf8_t b = *(const bf8_t*)(Wp1 + (((ct * 4 + kb) * 64 + lane) << 3));
            acc = __builtin_amdgcn_mfma_f32_16x16x32_bf16(a[kb], b, acc, 0, 0, 0);
        }
        float ws = as1[ct * 16 + m], wd = ad1[ct * 16 + m];
        #pragma unroll
        for (int r = 0; r < 4; r++) {
            sacc[r] += acc[r] * ws;
            dacc[r] += acc[r] * wd;
            tlh[(q * 4 + r) * 40 + ct * 16 + m] = f2bf(acc[r]);
        }
    }
    #pragma unroll
    for (int ct = 0; ct < 2; ct++) {           // skip (f32)
        f4_t acc = {0.f, 0.f, 0.f, 0.f};
        #pragma unroll
        for (int kb = 0; kb < 4; kb++) {
            bf8_t b = *(const bf8_t*)(lWp1 + (((ct * 4 + kb) * 64 + lane) << 3));
            acc = __builtin_amdgcn_mfma_f32_16x16x32_bf16(a[kb], b, acc, 0, 0, 0);
        }
        #pragma unroll
        for (int r = 0; r < 4; r++)
            tls[(q * 4 + r) * 36 + ct * 16 + m] = acc[r];
    }
    if (drow < N) {
        *(uint4*)((short*)h1 + (size_t)drow * 32 + qt * 8) =
            *(const uint4*)(tlh + r4 * 40 + qt * 8);
        float* dst = skipb + (size_t)drow * 32 + qt * 8;
        const float* srcp = tls + r4 * 36 + qt * 8;
        *(uint4*)(dst) = *(const uint4*)(srcp);
        *(uint4*)(dst + 4) = *(const uint4*)(srcp + 4);
    }
    #pragma unroll
    for (int r = 0; r < 4; r++) {
        float s = sacc[r], d = dacc[r];
        #pragma unroll
        for (int off = 1; off < 16; off <<= 1) {
            s += __shfl_xor(s, off);
            d += __shfl_xor(d, off);
        }
        if (m == 0) {
            int row = rowbase + q * 4 + r;
            if (row < N) { a1s[row] = s; a1d[row] = d; }
        }
    }
}

// ---------- aggregation: 16-lane edge groups, 4 edges in flight ----------

__global__ __launch_bounds__(256) void k_agg0(
    const int* __restrict__ rowstart, const unsigned short* __restrict__ esrc,
    const unsigned int* __restrict__ h0u,              // row = 64 uints (bf16x2)
    const float* __restrict__ a0s, const float* __restrict__ a0d,
    const float* __restrict__ bc0,                     // bias0+linb0 [128]
    unsigned int* __restrict__ h1in_u,                 // in: skip0 bf16, out: ELU
    int n) {
    int node = (blockIdx.x * 256 + threadIdx.x) >> 6;
    int lane = threadIdx.x & 63;
    if (node >= n) return;
    int g = lane >> 4, t = lane & 15, hd = t >> 2;
    float ad = a0d[node * 4 + hd];
    int s0 = rowstart[node], s1 = rowstart[node + 1];
    float den = 0.f;
    float acc[8];
    #pragma unroll
    for (int k = 0; k < 8; k++) acc[k] = 0.f;
    int i = s0 + g;
    for (; i + 12 < s1; i += 16) {             // 4 edges/group in flight
        int sE[4]; float e[4]; uint4 p[4];
        #pragma unroll
        for (int j = 0; j < 4; j++) sE[j] = esrc[i + 4 * j];
        #pragma unroll
        for (int j = 0; j < 4; j++) e[j] = a0s[sE[j] * 4 + hd] + ad;
        #pragma unroll
        for (int j = 0; j < 4; j++) p[j] = *(const uint4*)(h0u + (size_t)sE[j] * 64 + t * 4);
        #pragma unroll
        for (int j = 0; j < 4; j++) {
            float wgt = lrexp(e[j]);
            den += wgt;
            acc[0] += wgt * blo(p[j].x); acc[1] += wgt * bhi(p[j].x);
            acc[2] += wgt * blo(p[j].y); acc[3] += wgt * bhi(p[j].y);
            acc[4] += wgt * blo(p[j].z); acc[5] += wgt * bhi(p[j].z);
            acc[6] += wgt * blo(p[j].w); acc[7] += wgt * bhi(p[j].w);
        }
    }
    for (; i < s1; i += 4) {
        int s = esrc[i];
        float wv = lrexp(a0s[s * 4 + hd] + ad);
        uint4 p = *(const uint4*)(h0u + (size_t)s * 64 + t * 4);
        den += wv;
        acc[0] += wv * blo(p.x); acc[1] += wv * bhi(p.x);
        acc[2] += wv * blo(p.y); acc[3] += wv * bhi(p.y);
        acc[4] += wv * blo(p.z); acc[5] += wv * bhi(p.z);
        acc[6] += wv * blo(p.w); acc[7] += wv * bhi(p.w);
    }
    #pragma unroll
    for (int k = 0; k < 8; k++) {
        acc[k] += __shfl_xor(acc[k], 16);
        acc[k] += __shfl_xor(acc[k], 32);
    }
    den += __shfl_xor(den, 16);
    den += __shfl_xor(den, 32);
    if (g == 0) {
        float inv = 1.0f / (den + 1e-16f);
        uint4 sp = *(const uint4*)(h1in_u + (size_t)node * 64 + t * 4); // skip0
        int c0 = t * 8;
        float o[8];
        o[0] = acc[0] * inv + blo(sp.x) + bc0[c0 + 0];
        o[1] = acc[1] * inv + bhi(sp.x) + bc0[c0 + 1];
        o[2] = acc[2] * inv + blo(sp.y) + bc0[c0 + 2];
        o[3] = acc[3] * inv + bhi(sp.y) + bc0[c0 + 3];
        o[4] = acc[4] * inv + blo(sp.z) + bc0[c0 + 4];
        o[5] = acc[5] * inv + bhi(sp.z) + bc0[c0 + 5];
        o[6] = acc[6] * inv + blo(sp.w) + bc0[c0 + 6];
        o[7] = acc[7] * inv + bhi(sp.w) + bc0[c0 + 7];
        #pragma unroll
        for (int k = 0; k < 8; k++)
            o[k] = (o[k] > 0.f) ? o[k] : (__expf(o[k]) - 1.f);  // ELU
        uint4 res;
        res.x = (unsigned int)(unsigned short)f2bf(o[0]) | ((unsigned int)(unsigned short)f2bf(o[1]) << 16);
        res.y = (unsigned int)(unsigned short)f2bf(o[2]) | ((unsigned int)(unsigned short)f2bf(o[3]) << 16);
        res.z = (unsigned int)(unsigned short)f2bf(o[4]) | ((unsigned int)(unsigned short)f2bf(o[5]) << 16);
        res.w = (unsigned int)(unsigned short)f2bf(o[6]) | ((unsigned int)(unsigned short)f2bf(o[7]) << 16);
        *(uint4*)(h1in_u + (size_t)node * 64 + t * 4) = res;
    }
}

__global__ __launch_bounds__(256) void k_agg1(
    const int* __restrict__ rowstart, const unsigned short* __restrict__ esrc,
    const __hip_bfloat16* __restrict__ h1,
    const float* __restrict__ a1s, const float* __restrict__ a1d,
    const float* __restrict__ bc1,                     // bias1+linb1 [32]
    float* __restrict__ out, int n) {
    int node = (blockIdx.x * 256 + threadIdx.x) >> 6;
    int lane = threadIdx.x & 63;
    if (node >= n) return;
    int g = lane >> 4, t = lane & 15;
    float ad = a1d[node];
    int s0 = rowstart[node], s1 = rowstart[node + 1];
    const unsigned int* h1w = (const unsigned int*)h1;  // row = 16 uints
    float den = 0.f, acc0 = 0.f, acc1 = 0.f;
    int i = s0 + g;
    for (; i + 12 < s1; i += 16) {             // 4 edges/group in flight
        int sE[4]; float e[4]; unsigned int p[4];
        #pragma unroll
        for (int j = 0; j < 4; j++) sE[j] = esrc[i + 4 * j];
        #pragma unroll
        for (int j = 0; j < 4; j++) e[j] = a1s[sE[j]] + ad;
        #pragma unroll
        for (int j = 0; j < 4; j++) p[j] = h1w[(size_t)sE[j] * 16 + t];
        #pragma unroll
        for (int j = 0; j < 4; j++) {
            float wgt = lrexp(e[j]);
            den += wgt;
            acc0 += wgt * blo(p[j]);
            acc1 += wgt * bhi(p[j]);
        }
    }
    for (; i < s1; i += 4) {
        int s = esrc[i];
        float wv = lrexp(a1s[s] + ad);
        unsigned int p = h1w[(size_t)s * 16 + t];
        den += wv; acc0 += wv * blo(p); acc1 += wv * bhi(p);
    }
    acc0 += __shfl_xor(acc0, 16); acc0 += __shfl_xor(acc0, 32);
    acc1 += __shfl_xor(acc1, 16); acc1 += __shfl_xor(acc1, 32);
    den  += __shfl_xor(den, 16);  den  += __shfl_xor(den, 32);
    if (g == 0) {
        float inv = 1.0f / (den + 1e-16f);
        int c0 = t * 2;
        size_t idx = (size_t)node * 32 + c0;
        float2 sk = *(const float2*)(out + idx);     // skip1
        float2 r;
        r.x = acc0 * inv + sk.x + bc1[c0];
        r.y = acc1 * inv + sk.y + bc1[c0 + 1];
        *(float2*)(out + idx) = r;
    }
}

// ---------------- launch ----------------

extern "C" void kernel_launch(void* const* d_in, const int* in_sizes, int n_in,
                              void* d_out, int out_size, void* d_ws, size_t ws_size,
                              hipStream_t stream) {
    const float* x   = (const float*)d_in[0];
    const int*   ei  = (const int*)d_in[1];
    const float* W0  = (const float*)d_in[2];
    const float* as0 = (const float*)d_in[3];
    const float* ad0 = (const float*)d_in[4];
    const float* b0  = (const float*)d_in[5];
    const float* lW0 = (const float*)d_in[6];
    const float* lb0 = (const float*)d_in[7];
    const float* W1  = (const float*)d_in[8];
    const float* as1 = (const float*)d_in[9];
    const float* ad1 = (const float*)d_in[10];
    const float* b1  = (const float*)d_in[11];
    const float* lW1 = (const float*)d_in[12];
    const float* lb1 = (const float*)d_in[13];
    float* out = (float*)d_out;

    const int N = in_sizes[0] / 128;
    const int E = in_sizes[1] / 2;
    const int T = E + N;
    const int NBK  = (N + 255) >> 8;        // used buckets (196)
    const int NBBK = (T + 2047) / 2048;     // bucket blocks (416)

    // workspace carve-up (256B aligned), ~38 MB
    char* w = (char*)d_ws;
    auto alloc = [&](size_t bytes) -> char* {
        char* p = w; w += (bytes + 255) / 256 * 256; return p;
    };
    int* rowstart  = (int*)alloc((size_t)(N + 1) * 4);
    int* gcur      = (int*)alloc(NBUCK * 4);
    int* done      = (int*)alloc(4);
    int* bbase     = (int*)alloc(NBUCK * 4);
    unsigned int* bucketed = (unsigned int*)alloc((size_t)NBUCK * BCAP * 4);
    unsigned short* esrc = (unsigned short*)alloc((size_t)T * 2);
    float* aS      = (float*)alloc((size_t)N * 4 * 4);    // layer0 [N,4]; layer1 [N]
    float* aD      = (float*)alloc((size_t)N * 4 * 4);
    __hip_bfloat16* hbuf = (__hip_bfloat16*)alloc((size_t)N * 128 * 2); // h0 / h1
    __hip_bfloat16* h1in = (__hip_bfloat16*)alloc((size_t)N * 128 * 2); // skip0 -> ELU
    short* Wp0  = (short*)alloc(16384 * 2);
    short* lWp0 = (short*)alloc(16384 * 2);
    short* Wp1  = (short*)alloc(4096 * 2);
    short* lWp1 = (short*)alloc(4096 * 2);
    float* bc0  = (float*)alloc(128 * 4);
    float* bc1  = (float*)alloc(32 * 4);

    // L1: cursors; L2: weight-pack ∥ bucketing (+inline bucket scan)
    k_gz<<<1, NBUCK, 0, stream>>>(gcur, done);
    k_initbucket<<<64 + NBBK, 256, 0, stream>>>(ei, W0, lW0, W1, lW1,
                                                b0, lb0, b1, lb1,
                                                Wp0, lWp0, Wp1, lWp1, bc0, bc1,
                                                gcur, done, bbase, rowstart,
                                                bucketed, E, T, N);
    // L3: CSR fill ∥ gemm0(+att0)
    k_fillgemm0<<<NBK + (N + 63) / 64, 256, 0, stream>>>(
        bucketed, gcur, bbase, rowstart, esrc,
        x, Wp0, lWp0, as0, ad0, hbuf, h1in, aS, aD, N);
    // L4-L6
    k_agg0<<<(N + 3) / 4, 256, 0, stream>>>(rowstart, esrc, (const unsigned int*)hbuf,
                                            aS, aD, bc0, (unsigned int*)h1in, N);
    k_gemm1<<<(N + 63) / 64, 256, 0, stream>>>(h1in, Wp1, lWp1, as1, ad1,
                                               hbuf, out, aS, aD, N);
    k_agg1<<<(N + 3) / 4, 256, 0, stream>>>(rowstart, esrc, hbuf, aS, aD,
                                            bc1, out, N);
}

// Round 13
// 210.504 us; speedup vs baseline: 1.2674x; 1.2674x over previous
//
#include <hip/hip_runtime.h>
#include <hip/hip_bf16.h>

// GATNet 2-layer GAT, N=50000, E=800000 (+N self loops). f32 in/out, bf16 MFMA.
// Round-13: revert r12's inline-bscan tail (per-block __threadfence drain +
// serial 1-block scan cost ~40us). k_initbucket = weight-pack ∥ bucketing only;
// k_bscan separate again. Keep fill∥gemm0 fusion + 4-deep agg pipelines.

typedef __attribute__((ext_vector_type(8))) short bf8_t;   // 8 x bf16 (4 VGPRs)
typedef __attribute__((ext_vector_type(4))) float f4_t;

#define NBUCK 256      // bucket table size (used buckets = (N+255)>>8 = 196)
#define BCAP  8192     // per-bucket capacity (expected ~4343, uniform random)

__device__ inline short f2bf(float f) {
    return (short)__builtin_bit_cast(unsigned short, __float2bfloat16(f));
}
__device__ inline float blo(unsigned int p) { return __uint_as_float(p << 16); }
__device__ inline float bhi(unsigned int p) { return __uint_as_float(p & 0xffff0000u); }
__device__ inline float lrexp(float e) {
    e = (e > 0.f) ? e : 0.2f * e;          // leaky_relu(0.2); |e|<~12 -> exp safe
    return __expf(e);
}

// ---------------- tiny init: bucket cursors ----------------
__global__ void k_gz(int* __restrict__ gcur) {
    gcur[threadIdx.x] = threadIdx.x * BCAP;
}

// ---- fused: weight pack (blocks 0..63)  |  edge bucketing (blocks 64..) ----
// Wp[((ct*4+kb)*64 + lane)*8 + j] = W[ct*16 + (lane&15)][kb*32 + (lane>>4)*8 + j]
__global__ __launch_bounds__(256) void k_initbucket(
    const int* __restrict__ ei,
    const float* __restrict__ W0, const float* __restrict__ lW0,
    const float* __restrict__ W1, const float* __restrict__ lW1,
    const float* __restrict__ b0, const float* __restrict__ lb0,
    const float* __restrict__ b1, const float* __restrict__ lb1,
    short* __restrict__ Wp0, short* __restrict__ lWp0,
    short* __restrict__ Wp1, short* __restrict__ lWp1,
    float* __restrict__ bc0, float* __restrict__ bc1,
    int* __restrict__ gcur,
    unsigned int* __restrict__ bucketed, int E, int T) {
    __shared__ int hist[NBUCK];
    __shared__ int gbase[NBUCK];
    int tid = threadIdx.x;

    if (blockIdx.x < 64) {                 // ---- weight/bias pack ----
        int i = blockIdx.x * 256 + tid;    // 0..16383
        {
            int j = i & 7, lane = (i >> 3) & 63, kc = i >> 9;
            int kb = kc & 3, ct = kc >> 2;
            int src = (ct * 16 + (lane & 15)) * 128 + kb * 32 + (lane >> 4) * 8 + j;
            Wp0[i]  = f2bf(W0[src]);
            lWp0[i] = f2bf(lW0[src]);
            if (i < 4096) {
                Wp1[i]  = f2bf(W1[src]);
                lWp1[i] = f2bf(lW1[src]);
            }
        }
        if (i < 128) bc0[i] = b0[i] + lb0[i];
        else if (i < 160) bc1[i - 128] = b1[i - 128] + lb1[i - 128];
        return;
    }

    // ---- bucketing: 2048 edges/block, LDS-ranked runs ----
    int bb = blockIdx.x - 64;
    hist[tid] = 0;
    __syncthreads();
    int base = bb * 2048;
    unsigned int pk[8]; int rk[8]; int bk[8];
    #pragma unroll
    for (int j = 0; j < 8; j++) {
        int e = base + j * 256 + tid;
        if (e < T) {
            int src, dst;
            if (e < E) { src = ei[e]; dst = ei[E + e]; }
            else       { src = e - E; dst = src; }          // self-loops
            int b = dst >> 8;
            pk[j] = ((unsigned int)dst << 16) | (unsigned int)src;
            bk[j] = b;
            rk[j] = atomicAdd(&hist[b], 1);
        } else bk[j] = -1;
    }
    __syncthreads();
    int h = hist[tid];
    if (h > 0) gbase[tid] = atomicAdd(&gcur[tid], h);
    __syncthreads();
    #pragma unroll
    for (int j = 0; j < 8; j++)
        if (bk[j] >= 0)
            bucketed[gbase[bk[j]] + rk[j]] = pk[j];
}

// exclusive scan of bucket totals -> bucket bases; grand total -> rowstart[N]
__global__ void k_bscan(const int* __restrict__ gcur, int* __restrict__ bbase,
                        int* __restrict__ rowstart, int n) {
    __shared__ int buf[NBUCK];
    int t = threadIdx.x;
    int v = gcur[t] - t * BCAP;
    buf[t] = v;
    __syncthreads();
    for (int off = 1; off < NBUCK; off <<= 1) {
        int tv = (t >= off) ? buf[t - off] : 0;
        __syncthreads();
        buf[t] += tv;
        __syncthreads();
    }
    bbase[t] = buf[t] - v;                 // exclusive
    if (t == NBUCK - 1) rowstart[n] = buf[t];
}

// ---------------- fused: CSR fill (blocks 0..NBK-1) | GEMM0 (rest) ----------
// fill: one block per bucket; LDS histogram+scan -> rowstart slice + esrc fill.
// gemm0: A-frag lane=A[m=lane&15][k=(lane>>4)*8+j]; B from packed tables;
// C/D col=lane&15,row=(lane>>4)*4+reg (m89-verified); LDS-staged coalesced out.

#define TSTR 136   // LDS tile row stride in shorts (272B, 16B-aligned)

__global__ __launch_bounds__(256) void k_fillgemm0(
    const unsigned int* __restrict__ bucketed, const int* __restrict__ gcur,
    const int* __restrict__ bbase, int* __restrict__ rowstart,
    unsigned short* __restrict__ esrc,
    const float* __restrict__ x,
    const short* __restrict__ Wp0, const short* __restrict__ lWp0,
    const float* __restrict__ as0, const float* __restrict__ ad0,
    __hip_bfloat16* __restrict__ h0, __hip_bfloat16* __restrict__ skipb,
    float* __restrict__ a0s, float* __restrict__ a0d, int N) {
    __shared__ int ihist[256];
    __shared__ int incl[256];
    __shared__ short tile[4][16 * TSTR];
    int NBK = (N + 255) >> 8;

    if ((int)blockIdx.x < NBK) {           // ---- CSR fill ----
        int b = blockIdx.x, t = threadIdx.x;
        int nodebase = b << 8;
        int used = gcur[b] - b * BCAP;
        const unsigned int* bk = bucketed + (size_t)b * BCAP;
        ihist[t] = 0;
        __syncthreads();
        for (int i = t; i < used; i += 256)
            atomicAdd(&ihist[(bk[i] >> 16) - nodebase], 1);
        __syncthreads();
        int v = ihist[t];
        incl[t] = v;
        __syncthreads();
        for (int off = 1; off < 256; off <<= 1) {
            int tv = (t >= off) ? incl[t - off] : 0;
            __syncthreads();
            incl[t] += tv;
            __syncthreads();
        }
        int myexcl = incl[t] - v;
        int rbase = bbase[b];
        int node = nodebase + t;
        if (node < N) rowstart[node] = rbase + myexcl;
        __syncthreads();
        ihist[t] = myexcl;                 // reuse as fill cursor
        __syncthreads();
        for (int i = t; i < used; i += 256) {
            unsigned int p = bk[i];
            int pos = atomicAdd(&ihist[(p >> 16) - nodebase], 1);
            esrc[rbase + pos] = (unsigned short)(p & 0xffffu);
        }
        return;
    }

    // ---- GEMM0 + fused att0 ----
    int bx = blockIdx.x - NBK;
    int wv = threadIdx.x >> 6, lane = threadIdx.x & 63;
    int rowbase = bx * 64 + wv * 16;
    int m = lane & 15, q = lane >> 4;
    int arow = rowbase + m; if (arow >= N) arow = N - 1;
    bf8_t a[4];
    #pragma unroll
    for (int kb = 0; kb < 4; kb++) {
        const float4* px = (const float4*)(x + (size_t)arow * 128 + kb * 32 + q * 8);
        float4 lo = px[0], hi = px[1];
        bf8_t f;
        f[0] = f2bf(lo.x); f[1] = f2bf(lo.y); f[2] = f2bf(lo.z); f[3] = f2bf(lo.w);
        f[4] = f2bf(hi.x); f[5] = f2bf(hi.y); f[6] = f2bf(hi.z); f[7] = f2bf(hi.w);
        a[kb] = f;
    }
    float sacc[4][4], dacc[4][4];
    #pragma unroll
    for (int h = 0; h < 4; h++)
        #pragma unroll
        for (int r = 0; r < 4; r++) { sacc[h][r] = 0.f; dacc[h][r] = 0.f; }
    short* tl = tile[wv];
    int r4 = lane >> 2, qt = lane & 3;     // drain mapping: row, 64B quarter
    int drow = rowbase + r4;

    // phase 1: h0 (cts 0..7) + att accumulation
    #pragma unroll
    for (int ct = 0; ct < 8; ct++) {
        f4_t acc = {0.f, 0.f, 0.f, 0.f};
        #pragma unroll
        for (int kb = 0; kb < 4; kb++) {
            bf8_t b = *(const bf8_t*)(Wp0 + (((ct * 4 + kb) * 64 + lane) << 3));
            acc = __builtin_amdgcn_mfma_f32_16x16x32_bf16(a[kb], b, acc, 0, 0, 0);
        }
        int hd = ct >> 1;
        float ws = as0[ct * 16 + m], wd = ad0[ct * 16 + m];
        #pragma unroll
        for (int r = 0; r < 4; r++) {
            sacc[hd][r] += acc[r] * ws;
            dacc[hd][r] += acc[r] * wd;
            tl[(q * 4 + r) * TSTR + ct * 16 + m] = f2bf(acc[r]);
        }
    }
    if (drow < N) {
        short* dst = (short*)h0 + (size_t)drow * 128 + qt * 32;
        const short* srcp = tl + r4 * TSTR + qt * 32;
        #pragma unroll
        for (int s = 0; s < 4; s++)
            *(uint4*)(dst + s * 8) = *(const uint4*)(srcp + s * 8);
    }

    // phase 2: skip (cts 8..15) -> same tile, drain to skipb
    #pragma unroll
    for (int ct = 0; ct < 8; ct++) {
        f4_t acc = {0.f, 0.f, 0.f, 0.f};
        #pragma unroll
        for (int kb = 0; kb < 4; kb++) {
            bf8_t b = *(const bf8_t*)(lWp0 + (((ct * 4 + kb) * 64 + lane) << 3));
            acc = __builtin_amdgcn_mfma_f32_16x16x32_bf16(a[kb], b, acc, 0, 0, 0);
        }
        #pragma unroll
        for (int r = 0; r < 4; r++)
            tl[(q * 4 + r) * TSTR + ct * 16 + m] = f2bf(acc[r]);
    }
    if (drow < N) {
        short* dst = (short*)skipb + (size_t)drow * 128 + qt * 32;
        const short* srcp = tl + r4 * TSTR + qt * 32;
        #pragma unroll
        for (int s = 0; s < 4; s++)
            *(uint4*)(dst + s * 8) = *(const uint4*)(srcp + s * 8);
    }

    // att logits: reduce over the 16 m-lanes
    #pragma unroll
    for (int h = 0; h < 4; h++)
        #pragma unroll
        for (int r = 0; r < 4; r++) {
            float s = sacc[h][r], d = dacc[h][r];
            #pragma unroll
            for (int off = 1; off < 16; off <<= 1) {
                s += __shfl_xor(s, off);
                d += __shfl_xor(d, off);
            }
            sacc[h][r] = s; dacc[h][r] = d;
        }
    if (m < 4) {
        #pragma unroll
        for (int r = 0; r < 4; r++) {
            int row = rowbase + q * 4 + r;
            if (row < N) {
                float sv = (m == 0) ? sacc[0][r] : (m == 1) ? sacc[1][r]
                         : (m == 2) ? sacc[2][r] : sacc[3][r];
                float dv = (m == 0) ? dacc[0][r] : (m == 1) ? dacc[1][r]
                         : (m == 2) ? dacc[2][r] : dacc[3][r];
                a0s[row * 4 + m] = sv;
                a0d[row * 4 + m] = dv;
            }
        }
    }
}

// ---------------- GEMM1 + fused att1 ----------------

__global__ __launch_bounds__(256) void k_gemm1(
    const __hip_bfloat16* __restrict__ hin,
    const short* __restrict__ Wp1, const short* __restrict__ lWp1,
    const float* __restrict__ as1, const float* __restrict__ ad1,
    __hip_bfloat16* __restrict__ h1, float* __restrict__ skipb /* = d_out */,
    float* __restrict__ a1s, float* __restrict__ a1d, int N) {
    __shared__ short th[4][16 * 40];           // h1 tile (stride 40 shorts)
    __shared__ float ts[4][16 * 36];           // skip tile (stride 36 floats)
    int wv = threadIdx.x >> 6, lane = threadIdx.x & 63;
    int rowbase = blockIdx.x * 64 + wv * 16;
    int m = lane & 15, q = lane >> 4;
    int arow = rowbase + m; if (arow >= N) arow = N - 1;
    const short* xs = (const short*)hin;
    bf8_t a[4];
    #pragma unroll
    for (int kb = 0; kb < 4; kb++)
        a[kb] = *(const bf8_t*)(xs + (size_t)arow * 128 + kb * 32 + q * 8);
    float sacc[4], dacc[4];
    #pragma unroll
    for (int r = 0; r < 4; r++) { sacc[r] = 0.f; dacc[r] = 0.f; }
    short* tlh = th[wv];
    float* tls = ts[wv];
    int r4 = lane >> 2, qt = lane & 3;
    int drow = rowbase + r4;

    #pragma unroll
    for (int ct = 0; ct < 2; ct++) {           // h1 + att
        f4_t acc = {0.f, 0.f, 0.f, 0.f};
        #pragma unroll
        for (int kb = 0; kb < 4; kb++) {
            bf8_t b = *(const bf8_t*)(Wp1 + (((ct * 4 + kb) * 64 + lane) << 3));
            acc = __builtin_amdgcn_mfma_f32_16x16x32_bf16(a[kb], b, acc, 0, 0, 0);
        }
        float ws = as1[ct * 16 + m], wd = ad1[ct * 16 + m];
        #pragma unroll
        for (int r = 0; r < 4; r++) {
            sacc[r] += acc[r] * ws;
            dacc[r] += acc[r] * wd;
            tlh[(q * 4 + r) * 40 + ct * 16 + m] = f2bf(acc[r]);
        }
    }
    #pragma unroll
    for (int ct = 0; ct < 2; ct++) {           // skip (f32)
        f4_t acc = {0.f, 0.f, 0.f, 0.f};
        #pragma unroll
        for (int kb = 0; kb < 4; kb++) {
            bf8_t b = *(const bf8_t*)(lWp1 + (((ct * 4 + kb) * 64 + lane) << 3));
            acc = __builtin_amdgcn_mfma_f32_16x16x32_bf16(a[kb], b, acc, 0, 0, 0);
        }
        #pragma unroll
        for (int r = 0; r < 4; r++)
            tls[(q * 4 + r) * 36 + ct * 16 + m] = acc[r];
    }
    if (drow < N) {
        *(uint4*)((short*)h1 + (size_t)drow * 32 + qt * 8) =
            *(const uint4*)(tlh + r4 * 40 + qt * 8);
        float* dst = skipb + (size_t)drow * 32 + qt * 8;
        const float* srcp = tls + r4 * 36 + qt * 8;
        *(uint4*)(dst) = *(const uint4*)(srcp);
        *(uint4*)(dst + 4) = *(const uint4*)(srcp + 4);
    }
    #pragma unroll
    for (int r = 0; r < 4; r++) {
        float s = sacc[r], d = dacc[r];
        #pragma unroll
        for (int off = 1; off < 16; off <<= 1) {
            s += __shfl_xor(s, off);
            d += __shfl_xor(d, off);
        }
        if (m == 0) {
            int row = rowbase + q * 4 + r;
            if (row < N) { a1s[row] = s; a1d[row] = d; }
        }
    }
}

// ---------- aggregation: 16-lane edge groups, 4 edges in flight ----------

__global__ __launch_bounds__(256) void k_agg0(
    const int* __restrict__ rowstart, const unsigned short* __restrict__ esrc,
    const unsigned int* __restrict__ h0u,              // row = 64 uints (bf16x2)
    const float* __restrict__ a0s, const float* __restrict__ a0d,
    const float* __restrict__ bc0,                     // bias0+linb0 [128]
    unsigned int* __restrict__ h1in_u,                 // in: skip0 bf16, out: ELU
    int n) {
    int node = (blockIdx.x * 256 + threadIdx.x) >> 6;
    int lane = threadIdx.x & 63;
    if (node >= n) return;
    int g = lane >> 4, t = lane & 15, hd = t >> 2;
    float ad = a0d[node * 4 + hd];
    int s0 = rowstart[node], s1 = rowstart[node + 1];
    float den = 0.f;
    float acc[8];
    #pragma unroll
    for (int k = 0; k < 8; k++) acc[k] = 0.f;
    int i = s0 + g;
    for (; i + 12 < s1; i += 16) {             // 4 edges/group in flight
        int sE[4]; float e[4]; uint4 p[4];
        #pragma unroll
        for (int j = 0; j < 4; j++) sE[j] = esrc[i + 4 * j];
        #pragma unroll
        for (int j = 0; j < 4; j++) e[j] = a0s[sE[j] * 4 + hd] + ad;
        #pragma unroll
        for (int j = 0; j < 4; j++) p[j] = *(const uint4*)(h0u + (size_t)sE[j] * 64 + t * 4);
        #pragma unroll
        for (int j = 0; j < 4; j++) {
            float wgt = lrexp(e[j]);
            den += wgt;
            acc[0] += wgt * blo(p[j].x); acc[1] += wgt * bhi(p[j].x);
            acc[2] += wgt * blo(p[j].y); acc[3] += wgt * bhi(p[j].y);
            acc[4] += wgt * blo(p[j].z); acc[5] += wgt * bhi(p[j].z);
            acc[6] += wgt * blo(p[j].w); acc[7] += wgt * bhi(p[j].w);
        }
    }
    for (; i < s1; i += 4) {
        int s = esrc[i];
        float wv = lrexp(a0s[s * 4 + hd] + ad);
        uint4 p = *(const uint4*)(h0u + (size_t)s * 64 + t * 4);
        den += wv;
        acc[0] += wv * blo(p.x); acc[1] += wv * bhi(p.x);
        acc[2] += wv * blo(p.y); acc[3] += wv * bhi(p.y);
        acc[4] += wv * blo(p.z); acc[5] += wv * bhi(p.z);
        acc[6] += wv * blo(p.w); acc[7] += wv * bhi(p.w);
    }
    #pragma unroll
    for (int k = 0; k < 8; k++) {
        acc[k] += __shfl_xor(acc[k], 16);
        acc[k] += __shfl_xor(acc[k], 32);
    }
    den += __shfl_xor(den, 16);
    den += __shfl_xor(den, 32);
    if (g == 0) {
        float inv = 1.0f / (den + 1e-16f);
        uint4 sp = *(const uint4*)(h1in_u + (size_t)node * 64 + t * 4); // skip0
        int c0 = t * 8;
        float o[8];
        o[0] = acc[0] * inv + blo(sp.x) + bc0[c0 + 0];
        o[1] = acc[1] * inv + bhi(sp.x) + bc0[c0 + 1];
        o[2] = acc[2] * inv + blo(sp.y) + bc0[c0 + 2];
        o[3] = acc[3] * inv + bhi(sp.y) + bc0[c0 + 3];
        o[4] = acc[4] * inv + blo(sp.z) + bc0[c0 + 4];
        o[5] = acc[5] * inv + bhi(sp.z) + bc0[c0 + 5];
        o[6] = acc[6] * inv + blo(sp.w) + bc0[c0 + 6];
        o[7] = acc[7] * inv + bhi(sp.w) + bc0[c0 + 7];
        #pragma unroll
        for (int k = 0; k < 8; k++)
            o[k] = (o[k] > 0.f) ? o[k] : (__expf(o[k]) - 1.f);  // ELU
        uint4 res;
        res.x = (unsigned int)(unsigned short)f2bf(o[0]) | ((unsigned int)(unsigned short)f2bf(o[1]) << 16);
        res.y = (unsigned int)(unsigned short)f2bf(o[2]) | ((unsigned int)(unsigned short)f2bf(o[3]) << 16);
        res.z = (unsigned int)(unsigned short)f2bf(o[4]) | ((unsigned int)(unsigned short)f2bf(o[5]) << 16);
        res.w = (unsigned int)(unsigned short)f2bf(o[6]) | ((unsigned int)(unsigned short)f2bf(o[7]) << 16);
        *(uint4*)(h1in_u + (size_t)node * 64 + t * 4) = res;
    }
}

__global__ __launch_bounds__(256) void k_agg1(
    const int* __restrict__ rowstart, const unsigned short* __restrict__ esrc,
    const __hip_bfloat16* __restrict__ h1,
    const float* __restrict__ a1s, const float* __restrict__ a1d,
    const float* __restrict__ bc1,                     // bias1+linb1 [32]
    float* __restrict__ out, int n) {
    int node = (blockIdx.x * 256 + threadIdx.x) >> 6;
    int lane = threadIdx.x & 63;
    if (node >= n) return;
    int g = lane >> 4, t = lane & 15;
    float ad = a1d[node];
    int s0 = rowstart[node], s1 = rowstart[node + 1];
    const unsigned int* h1w = (const unsigned int*)h1;  // row = 16 uints
    float den = 0.f, acc0 = 0.f, acc1 = 0.f;
    int i = s0 + g;
    for (; i + 12 < s1; i += 16) {             // 4 edges/group in flight
        int sE[4]; float e[4]; unsigned int p[4];
        #pragma unroll
        for (int j = 0; j < 4; j++) sE[j] = esrc[i + 4 * j];
        #pragma unroll
        for (int j = 0; j < 4; j++) e[j] = a1s[sE[j]] + ad;
        #pragma unroll
        for (int j = 0; j < 4; j++) p[j] = h1w[(size_t)sE[j] * 16 + t];
        #pragma unroll
        for (int j = 0; j < 4; j++) {
            float wgt = lrexp(e[j]);
            den += wgt;
            acc0 += wgt * blo(p[j]);
            acc1 += wgt * bhi(p[j]);
        }
    }
    for (; i < s1; i += 4) {
        int s = esrc[i];
        float wv = lrexp(a1s[s] + ad);
        unsigned int p = h1w[(size_t)s * 16 + t];
        den += wv; acc0 += wv * blo(p); acc1 += wv * bhi(p);
    }
    acc0 += __shfl_xor(acc0, 16); acc0 += __shfl_xor(acc0, 32);
    acc1 += __shfl_xor(acc1, 16); acc1 += __shfl_xor(acc1, 32);
    den  += __shfl_xor(den, 16);  den  += __shfl_xor(den, 32);
    if (g == 0) {
        float inv = 1.0f / (den + 1e-16f);
        int c0 = t * 2;
        size_t idx = (size_t)node * 32 + c0;
        float2 sk = *(const float2*)(out + idx);     // skip1
        float2 r;
        r.x = acc0 * inv + sk.x + bc1[c0];
        r.y = acc1 * inv + sk.y + bc1[c0 + 1];
        *(float2*)(out + idx) = r;
    }
}

// ---------------- launch ----------------

extern "C" void kernel_launch(void* const* d_in, const int* in_sizes, int n_in,
                              void* d_out, int out_size, void* d_ws, size_t ws_size,
                              hipStream_t stream) {
    const float* x   = (const float*)d_in[0];
    const int*   ei  = (const int*)d_in[1];
    const float* W0  = (const float*)d_in[2];
    const float* as0 = (const float*)d_in[3];
    const float* ad0 = (const float*)d_in[4];
    const float* b0  = (const float*)d_in[5];
    const float* lW0 = (const float*)d_in[6];
    const float* lb0 = (const float*)d_in[7];
    const float* W1  = (const float*)d_in[8];
    const float* as1 = (const float*)d_in[9];
    const float* ad1 = (const float*)d_in[10];
    const float* b1  = (const float*)d_in[11];
    const float* lW1 = (const float*)d_in[12];
    const float* lb1 = (const float*)d_in[13];
    float* out = (float*)d_out;

    const int N = in_sizes[0] / 128;
    const int E = in_sizes[1] / 2;
    const int T = E + N;
    const int NBK  = (N + 255) >> 8;        // used buckets (196)
    const int NBBK = (T + 2047) / 2048;     // bucket blocks (416)

    // workspace carve-up (256B aligned), ~38 MB
    char* w = (char*)d_ws;
    auto alloc = [&](size_t bytes) -> char* {
        char* p = w; w += (bytes + 255) / 256 * 256; return p;
    };
    int* rowstart  = (int*)alloc((size_t)(N + 1) * 4);
    int* gcur      = (int*)alloc(NBUCK * 4);
    int* bbase     = (int*)alloc(NBUCK * 4);
    unsigned int* bucketed = (unsigned int*)alloc((size_t)NBUCK * BCAP * 4);
    unsigned short* esrc = (unsigned short*)alloc((size_t)T * 2);
    float* aS      = (float*)alloc((size_t)N * 4 * 4);    // layer0 [N,4]; layer1 [N]
    float* aD      = (float*)alloc((size_t)N * 4 * 4);
    __hip_bfloat16* hbuf = (__hip_bfloat16*)alloc((size_t)N * 128 * 2); // h0 / h1
    __hip_bfloat16* h1in = (__hip_bfloat16*)alloc((size_t)N * 128 * 2); // skip0 -> ELU
    short* Wp0  = (short*)alloc(16384 * 2);
    short* lWp0 = (short*)alloc(16384 * 2);
    short* Wp1  = (short*)alloc(4096 * 2);
    short* lWp1 = (short*)alloc(4096 * 2);
    float* bc0  = (float*)alloc(128 * 4);
    float* bc1  = (float*)alloc(32 * 4);

    // L1: cursors; L2: weight-pack ∥ bucketing; L3: bucket scan (1 block)
    k_gz<<<1, NBUCK, 0, stream>>>(gcur);
    k_initbucket<<<64 + NBBK, 256, 0, stream>>>(ei, W0, lW0, W1, lW1,
                                                b0, lb0, b1, lb1,
                                                Wp0, lWp0, Wp1, lWp1, bc0, bc1,
                                                gcur, bucketed, E, T);
    k_bscan<<<1, NBUCK, 0, stream>>>(gcur, bbase, rowstart, N);
    // L4: CSR fill ∥ gemm0(+att0)
    k_fillgemm0<<<NBK + (N + 63) / 64, 256, 0, stream>>>(
        bucketed, gcur, bbase, rowstart, esrc,
        x, Wp0, lWp0, as0, ad0, hbuf, h1in, aS, aD, N);
    // L5-L7
    k_agg0<<<(N + 3) / 4, 256, 0, stream>>>(rowstart, esrc, (const unsigned int*)hbuf,
                                            aS, aD, bc0, (unsigned int*)h1in, N);
    k_gemm1<<<(N + 63) / 64, 256, 0, stream>>>(h1in, Wp1, lWp1, as1, ad1,
                                               hbuf, out, aS, aD, N);
    k_agg1<<<(N + 3) / 4, 256, 0, stream>>>(rowstart, esrc, hbuf, aS, aD,
                                            bc1, out, N);
}

// Round 14
// 202.297 us; speedup vs baseline: 1.3188x; 1.0406x over previous
//
#include <hip/hip_runtime.h>
#include <hip/hip_bf16.h>

// GATNet 2-layer GAT, N=50000, E=800000 (+N self loops). f32 in/out, bf16 MFMA.
// Round-14: h0 stored as fp8-e4m3 (HW cvt_pk builtins) -> agg0 gathers 8B/lane
// instead of 16B (table 12.8->6.4MB, more L2 hits). k_bscan folded into the
// fill blocks of k_fillgemm0 (each self-scans bucket counts). Rest = r13.

typedef __attribute__((ext_vector_type(8))) short bf8_t;   // 8 x bf16 (4 VGPRs)
typedef __attribute__((ext_vector_type(4))) float f4_t;
typedef __attribute__((ext_vector_type(2))) float f2_t;

#define NBUCK 256      // bucket table size (used buckets = (N+255)>>8 = 196)
#define BCAP  8192     // per-bucket capacity (expected ~4343, uniform random)

__device__ inline short f2bf(float f) {
    return (short)__builtin_bit_cast(unsigned short, __float2bfloat16(f));
}
__device__ inline float blo(unsigned int p) { return __uint_as_float(p << 16); }
__device__ inline float bhi(unsigned int p) { return __uint_as_float(p & 0xffff0000u); }
__device__ inline float lrexp(float e) {
    e = (e > 0.f) ? e : 0.2f * e;          // leaky_relu(0.2); |e|<~12 -> exp safe
    return __expf(e);
}

// ---------------- tiny init: bucket cursors ----------------
__global__ void k_gz(int* __restrict__ gcur) {
    gcur[threadIdx.x] = threadIdx.x * BCAP;
}

// ---- fused: weight pack (blocks 0..63)  |  edge bucketing (blocks 64..) ----
__global__ __launch_bounds__(256) void k_initbucket(
    const int* __restrict__ ei,
    const float* __restrict__ W0, const float* __restrict__ lW0,
    const float* __restrict__ W1, const float* __restrict__ lW1,
    const float* __restrict__ b0, const float* __restrict__ lb0,
    const float* __restrict__ b1, const float* __restrict__ lb1,
    short* __restrict__ Wp0, short* __restrict__ lWp0,
    short* __restrict__ Wp1, short* __restrict__ lWp1,
    float* __restrict__ bc0, float* __restrict__ bc1,
    int* __restrict__ gcur,
    unsigned int* __restrict__ bucketed, int E, int T) {
    __shared__ int hist[NBUCK];
    __shared__ int gbase[NBUCK];
    int tid = threadIdx.x;

    if (blockIdx.x < 64) {                 // ---- weight/bias pack ----
        int i = blockIdx.x * 256 + tid;    // 0..16383
        {
            int j = i & 7, lane = (i >> 3) & 63, kc = i >> 9;
            int kb = kc & 3, ct = kc >> 2;
            int src = (ct * 16 + (lane & 15)) * 128 + kb * 32 + (lane >> 4) * 8 + j;
            Wp0[i]  = f2bf(W0[src]);
            lWp0[i] = f2bf(lW0[src]);
            if (i < 4096) {
                Wp1[i]  = f2bf(W1[src]);
                lWp1[i] = f2bf(lW1[src]);
            }
        }
        if (i < 128) bc0[i] = b0[i] + lb0[i];
        else if (i < 160) bc1[i - 128] = b1[i - 128] + lb1[i - 128];
        return;
    }

    // ---- bucketing: 2048 edges/block, LDS-ranked runs ----
    int bb = blockIdx.x - 64;
    hist[tid] = 0;
    __syncthreads();
    int base = bb * 2048;
    unsigned int pk[8]; int rk[8]; int bk[8];
    #pragma unroll
    for (int j = 0; j < 8; j++) {
        int e = base + j * 256 + tid;
        if (e < T) {
            int src, dst;
            if (e < E) { src = ei[e]; dst = ei[E + e]; }
            else       { src = e - E; dst = src; }          // self-loops
            int b = dst >> 8;
            pk[j] = ((unsigned int)dst << 16) | (unsigned int)src;
            bk[j] = b;
            rk[j] = atomicAdd(&hist[b], 1);
        } else bk[j] = -1;
    }
    __syncthreads();
    int h = hist[tid];
    if (h > 0) gbase[tid] = atomicAdd(&gcur[tid], h);
    __syncthreads();
    #pragma unroll
    for (int j = 0; j < 8; j++)
        if (bk[j] >= 0)
            bucketed[gbase[bk[j]] + rk[j]] = pk[j];
}

// ---------------- fused: CSR fill (blocks 0..NBK-1) | GEMM0 (rest) ----------
// fill: self-scans bucket counts (k_bscan folded in), then per-node LDS
// histogram+scan -> rowstart slice + esrc fill (all writes L2-local).
// gemm0: A-frag lane=A[m=lane&15][k=(lane>>4)*8+j]; B from packed tables;
// C/D col=lane&15,row=(lane>>4)*4+reg (m89-verified). h0 written as fp8-e4m3
// via byte-LDS tile; skip0 bf16 via short-LDS tile; coalesced drains.

#define TSTR 136   // short-tile row stride (272B); byte-tile row stride 136B

__global__ __launch_bounds__(256) void k_fillgemm0(
    const unsigned int* __restrict__ bucketed, const int* __restrict__ gcur,
    int* __restrict__ rowstart,
    unsigned short* __restrict__ esrc,
    const float* __restrict__ x,
    const short* __restrict__ Wp0, const short* __restrict__ lWp0,
    const float* __restrict__ as0, const float* __restrict__ ad0,
    unsigned char* __restrict__ h0f8, __hip_bfloat16* __restrict__ skipb,
    float* __restrict__ a0s, float* __restrict__ a0d, int N) {
    __shared__ int ihist[256];
    __shared__ int incl[256];
    __shared__ short tile[4][16 * TSTR];
    __shared__ unsigned char t8[4][16 * 136];
    int NBK = (N + 255) >> 8;

    if ((int)blockIdx.x < NBK) {           // ---- CSR fill ----
        int b = blockIdx.x, t = threadIdx.x;
        int nodebase = b << 8;
        // self-scan of bucket counts (replaces k_bscan)
        int cntt = gcur[t] - t * BCAP;
        incl[t] = cntt;
        __syncthreads();
        for (int off = 1; off < 256; off <<= 1) {
            int tv = (t >= off) ? incl[t - off] : 0;
            __syncthreads();
            incl[t] += tv;
            __syncthreads();
        }
        int rbase = (b > 0) ? incl[b - 1] : 0;
        if (b == 0 && t == 255) rowstart[N] = incl[255];
        int used = gcur[b] - b * BCAP;
        const unsigned int* bk = bucketed + (size_t)b * BCAP;
        __syncthreads();
        // per-node histogram
        ihist[t] = 0;
        __syncthreads();
        for (int i = t; i < used; i += 256)
            atomicAdd(&ihist[(bk[i] >> 16) - nodebase], 1);
        __syncthreads();
        int v = ihist[t];
        incl[t] = v;
        __syncthreads();
        for (int off = 1; off < 256; off <<= 1) {
            int tv = (t >= off) ? incl[t - off] : 0;
            __syncthreads();
            incl[t] += tv;
            __syncthreads();
        }
        int myexcl = incl[t] - v;
        int node = nodebase + t;
        if (node < N) rowstart[node] = rbase + myexcl;
        __syncthreads();
        ihist[t] = myexcl;                 // reuse as fill cursor
        __syncthreads();
        for (int i = t; i < used; i += 256) {
            unsigned int p = bk[i];
            int pos = atomicAdd(&ihist[(p >> 16) - nodebase], 1);
            esrc[rbase + pos] = (unsigned short)(p & 0xffffu);
        }
        return;
    }

    // ---- GEMM0 + fused att0 ----
    int bx = blockIdx.x - NBK;
    int wv = threadIdx.x >> 6, lane = threadIdx.x & 63;
    int rowbase = bx * 64 + wv * 16;
    int m = lane & 15, q = lane >> 4;
    int arow = rowbase + m; if (arow >= N) arow = N - 1;
    bf8_t a[4];
    #pragma unroll
    for (int kb = 0; kb < 4; kb++) {
        const float4* px = (const float4*)(x + (size_t)arow * 128 + kb * 32 + q * 8);
        float4 lo = px[0], hi = px[1];
        bf8_t f;
        f[0] = f2bf(lo.x); f[1] = f2bf(lo.y); f[2] = f2bf(lo.z); f[3] = f2bf(lo.w);
        f[4] = f2bf(hi.x); f[5] = f2bf(hi.y); f[6] = f2bf(hi.z); f[7] = f2bf(hi.w);
        a[kb] = f;
    }
    float sacc[4][4], dacc[4][4];
    #pragma unroll
    for (int h = 0; h < 4; h++)
        #pragma unroll
        for (int r = 0; r < 4; r++) { sacc[h][r] = 0.f; dacc[h][r] = 0.f; }
    short* tl = tile[wv];
    unsigned char* t8l = t8[wv];
    int r4 = lane >> 2, qt = lane & 3;     // drain mapping: row, quarter
    int drow = rowbase + r4;

    // phase 1: h0 (cts 0..7) as fp8-e4m3 + att accumulation
    #pragma unroll
    for (int ct = 0; ct < 8; ct++) {
        f4_t acc = {0.f, 0.f, 0.f, 0.f};
        #pragma unroll
        for (int kb = 0; kb < 4; kb++) {
            bf8_t b = *(const bf8_t*)(Wp0 + (((ct * 4 + kb) * 64 + lane) << 3));
            acc = __builtin_amdgcn_mfma_f32_16x16x32_bf16(a[kb], b, acc, 0, 0, 0);
        }
        int hd = ct >> 1;
        float ws = as0[ct * 16 + m], wd = ad0[ct * 16 + m];
        #pragma unroll
        for (int r = 0; r < 4; r++) {
            sacc[hd][r] += acc[r] * ws;
            dacc[hd][r] += acc[r] * wd;
            int pk8 = __builtin_amdgcn_cvt_pk_fp8_f32(acc[r], acc[r], 0, false);
            t8l[(q * 4 + r) * 136 + ct * 16 + m] = (unsigned char)(pk8 & 0xff);
        }
    }
    if (drow < N) {
        const unsigned char* sp8 = t8l + r4 * 136 + qt * 32;   // 8B-aligned
        uint2 w0 = ((const uint2*)sp8)[0];
        uint2 w1 = ((const uint2*)sp8)[1];
        uint2 w2 = ((const uint2*)sp8)[2];
        uint2 w3 = ((const uint2*)sp8)[3];
        uint4 o0 = make_uint4(w0.x, w0.y, w1.x, w1.y);
        uint4 o1 = make_uint4(w2.x, w2.y, w3.x, w3.y);
        unsigned char* dst = h0f8 + (size_t)drow * 128 + qt * 32;
        *(uint4*)dst = o0;
        *(uint4*)(dst + 16) = o1;
    }

    // phase 2: skip (cts 8..15) bf16 -> short tile, drain to skipb
    #pragma unroll
    for (int ct = 0; ct < 8; ct++) {
        f4_t acc = {0.f, 0.f, 0.f, 0.f};
        #pragma unroll
        for (int kb = 0; kb < 4; kb++) {
            bf8_t b = *(const bf8_t*)(lWp0 + (((ct * 4 + kb) * 64 + lane) << 3));
            acc = __builtin_amdgcn_mfma_f32_16x16x32_bf16(a[kb], b, acc, 0, 0, 0);
        }
        #pragma unroll
        for (int r = 0; r < 4; r++)
            tl[(q * 4 + r) * TSTR + ct * 16 + m] = f2bf(acc[r]);
    }
    if (drow < N) {
        short* dst = (short*)skipb + (size_t)drow * 128 + qt * 32;
        const short* srcp = tl + r4 * TSTR + qt * 32;
        #pragma unroll
        for (int s = 0; s < 4; s++)
            *(uint4*)(dst + s * 8) = *(const uint4*)(srcp + s * 8);
    }

    // att logits: reduce over the 16 m-lanes
    #pragma unroll
    for (int h = 0; h < 4; h++)
        #pragma unroll
        for (int r = 0; r < 4; r++) {
            float s = sacc[h][r], d = dacc[h][r];
            #pragma unroll
            for (int off = 1; off < 16; off <<= 1) {
                s += __shfl_xor(s, off);
                d += __shfl_xor(d, off);
            }
            sacc[h][r] = s; dacc[h][r] = d;
        }
    if (m < 4) {
        #pragma unroll
        for (int r = 0; r < 4; r++) {
            int row = rowbase + q * 4 + r;
            if (row < N) {
                float sv = (m == 0) ? sacc[0][r] : (m == 1) ? sacc[1][r]
                         : (m == 2) ? sacc[2][r] : sacc[3][r];
                float dv = (m == 0) ? dacc[0][r] : (m == 1) ? dacc[1][r]
                         : (m == 2) ? dacc[2][r] : dacc[3][r];
                a0s[row * 4 + m] = sv;
                a0d[row * 4 + m] = dv;
            }
        }
    }
}

// ---------------- GEMM1 + fused att1 ----------------

__global__ __launch_bounds__(256) void k_gemm1(
    const __hip_bfloat16* __restrict__ hin,
    const short* __restrict__ Wp1, const short* __restrict__ lWp1,
    const float* __restrict__ as1, const float* __restrict__ ad1,
    __hip_bfloat16* __restrict__ h1, float* __restrict__ skipb /* = d_out */,
    float* __restrict__ a1s, float* __restrict__ a1d, int N) {
    __shared__ short th[4][16 * 40];           // h1 tile (stride 40 shorts)
    __shared__ float ts[4][16 * 36];           // skip tile (stride 36 floats)
    int wv = threadIdx.x >> 6, lane = threadIdx.x & 63;
    int rowbase = blockIdx.x * 64 + wv * 16;
    int m = lane & 15, q = lane >> 4;
    int arow = rowbase + m; if (arow >= N) arow = N - 1;
    const short* xs = (const short*)hin;
    bf8_t a[4];
    #pragma unroll
    for (int kb = 0; kb < 4; kb++)
        a[kb] = *(const bf8_t*)(xs + (size_t)arow * 128 + kb * 32 + q * 8);
    float sacc[4], dacc[4];
    #pragma unroll
    for (int r = 0; r < 4; r++) { sacc[r] = 0.f; dacc[r] = 0.f; }
    short* tlh = th[wv];
    float* tls = ts[wv];
    int r4 = lane >> 2, qt = lane & 3;
    int drow = rowbase + r4;

    #pragma unroll
    for (int ct = 0; ct < 2; ct++) {           // h1 + att
        f4_t acc = {0.f, 0.f, 0.f, 0.f};
        #pragma unroll
        for (int kb = 0; kb < 4; kb++) {
            bf8_t b = *(const bf8_t*)(Wp1 + (((ct * 4 + kb) * 64 + lane) << 3));
            acc = __builtin_amdgcn_mfma_f32_16x16x32_bf16(a[kb], b, acc, 0, 0, 0);
        }
        float ws = as1[ct * 16 + m], wd = ad1[ct * 16 + m];
        #pragma unroll
        for (int r = 0; r < 4; r++) {
            sacc[r] += acc[r] * ws;
            dacc[r] += acc[r] * wd;
            tlh[(q * 4 + r) * 40 + ct * 16 + m] = f2bf(acc[r]);
        }
    }
    #pragma unroll
    for (int ct = 0; ct < 2; ct++) {           // skip (f32)
        f4_t acc = {0.f, 0.f, 0.f, 0.f};
        #pragma unroll
        for (int kb = 0; kb < 4; kb++) {
            bf8_t b = *(const bf8_t*)(lWp1 + (((ct * 4 + kb) * 64 + lane) << 3));
            acc = __builtin_amdgcn_mfma_f32_16x16x32_bf16(a[kb], b, acc, 0, 0, 0);
        }
        #pragma unroll
        for (int r = 0; r < 4; r++)
            tls[(q * 4 + r) * 36 + ct * 16 + m] = acc[r];
    }
    if (drow < N) {
        *(uint4*)((short*)h1 + (size_t)drow * 32 + qt * 8) =
            *(const uint4*)(tlh + r4 * 40 + qt * 8);
        float* dst = skipb + (size_t)drow * 32 + qt * 8;
        const float* srcp = tls + r4 * 36 + qt * 8;
        *(uint4*)(dst) = *(const uint4*)(srcp);
        *(uint4*)(dst + 4) = *(const uint4*)(srcp + 4);
    }
    #pragma unroll
    for (int r = 0; r < 4; r++) {
        float s = sacc[r], d = dacc[r];
        #pragma unroll
        for (int off = 1; off < 16; off <<= 1) {
            s += __shfl_xor(s, off);
            d += __shfl_xor(d, off);
        }
        if (m == 0) {
            int row = rowbase + q * 4 + r;
            if (row < N) { a1s[row] = s; a1d[row] = d; }
        }
    }
}

// ---------- aggregation: 16-lane edge groups, 4 edges in flight ----------

// h0 is fp8-e4m3: lane t gathers uint2 (8 fp8) at row src, channels 8t..8t+7.
__global__ __launch_bounds__(256) void k_agg0(
    const int* __restrict__ rowstart, const unsigned short* __restrict__ esrc,
    const uint2* __restrict__ h0f8,                    // row = 16 uint2 (128 fp8)
    const float* __restrict__ a0s, const float* __restrict__ a0d,
    const float* __restrict__ bc0,                     // bias0+linb0 [128]
    unsigned int* __restrict__ h1in_u,                 // in: skip0 bf16, out: ELU
    int n) {
    int node = (blockIdx.x * 256 + threadIdx.x) >> 6;
    int lane = threadIdx.x & 63;
    if (node >= n) return;
    int g = lane >> 4, t = lane & 15, hd = t >> 2;
    float ad = a0d[node * 4 + hd];
    int s0 = rowstart[node], s1 = rowstart[node + 1];
    float den = 0.f;
    float acc[8];
    #pragma unroll
    for (int k = 0; k < 8; k++) acc[k] = 0.f;
    int i = s0 + g;
    for (; i + 12 < s1; i += 16) {             // 4 edges/group in flight
        int sE[4]; float e[4]; uint2 p[4];
        #pragma unroll
        for (int j = 0; j < 4; j++) sE[j] = esrc[i + 4 * j];
        #pragma unroll
        for (int j = 0; j < 4; j++) e[j] = a0s[sE[j] * 4 + hd] + ad;
        #pragma unroll
        for (int j = 0; j < 4; j++) p[j] = h0f8[(size_t)sE[j] * 16 + t];
        #pragma unroll
        for (int j = 0; j < 4; j++) {
            float wgt = lrexp(e[j]);
            den += wgt;
            f2_t c01 = __builtin_amdgcn_cvt_pk_f32_fp8(p[j].x, false);
            f2_t c23 = __builtin_amdgcn_cvt_pk_f32_fp8(p[j].x, true);
            f2_t c45 = __builtin_amdgcn_cvt_pk_f32_fp8(p[j].y, false);
            f2_t c67 = __builtin_amdgcn_cvt_pk_f32_fp8(p[j].y, true);
            acc[0] += wgt * c01.x; acc[1] += wgt * c01.y;
            acc[2] += wgt * c23.x; acc[3] += wgt * c23.y;
            acc[4] += wgt * c45.x; acc[5] += wgt * c45.y;
            acc[6] += wgt * c67.x; acc[7] += wgt * c67.y;
        }
    }
    for (; i < s1; i += 4) {
        int s = esrc[i];
        float wgt = lrexp(a0s[s * 4 + hd] + ad);
        uint2 p = h0f8[(size_t)s * 16 + t];
        den += wgt;
        f2_t c01 = __builtin_amdgcn_cvt_pk_f32_fp8(p.x, false);
        f2_t c23 = __builtin_amdgcn_cvt_pk_f32_fp8(p.x, true);
        f2_t c45 = __builtin_amdgcn_cvt_pk_f32_fp8(p.y, false);
        f2_t c67 = __builtin_amdgcn_cvt_pk_f32_fp8(p.y, true);
        acc[0] += wgt * c01.x; acc[1] += wgt * c01.y;
        acc[2] += wgt * c23.x; acc[3] += wgt * c23.y;
        acc[4] += wgt * c45.x; acc[5] += wgt * c45.y;
        acc[6] += wgt * c67.x; acc[7] += wgt * c67.y;
    }
    #pragma unroll
    for (int k = 0; k < 8; k++) {
        acc[k] += __shfl_xor(acc[k], 16);
        acc[k] += __shfl_xor(acc[k], 32);
    }
    den += __shfl_xor(den, 16);
    den += __shfl_xor(den, 32);
    if (g == 0) {
        float inv = 1.0f / (den + 1e-16f);
        uint4 sp = *(const uint4*)(h1in_u + (size_t)node * 64 + t * 4); // skip0
        int c0 = t * 8;
        float o[8];
        o[0] = acc[0] * inv + blo(sp.x) + bc0[c0 + 0];
        o[1] = acc[1] * inv + bhi(sp.x) + bc0[c0 + 1];
        o[2] = acc[2] * inv + blo(sp.y) + bc0[c0 + 2];
        o[3] = acc[3] * inv + bhi(sp.y) + bc0[c0 + 3];
        o[4] = acc[4] * inv + blo(sp.z) + bc0[c0 + 4];
        o[5] = acc[5] * inv + bhi(sp.z) + bc0[c0 + 5];
        o[6] = acc[6] * inv + blo(sp.w) + bc0[c0 + 6];
        o[7] = acc[7] * inv + bhi(sp.w) + bc0[c0 + 7];
        #pragma unroll
        for (int k = 0; k < 8; k++)
            o[k] = (o[k] > 0.f) ? o[k] : (__expf(o[k]) - 1.f);  // ELU
        uint4 res;
        res.x = (unsigned int)(unsigned short)f2bf(o[0]) | ((unsigned int)(unsigned short)f2bf(o[1]) << 16);
        res.y = (unsigned int)(unsigned short)f2bf(o[2]) | ((unsigned int)(unsigned short)f2bf(o[3]) << 16);
        res.z = (unsigned int)(unsigned short)f2bf(o[4]) | ((unsigned int)(unsigned short)f2bf(o[5]) << 16);
        res.w = (unsigned int)(unsigned short)f2bf(o[6]) | ((unsigned int)(unsigned short)f2bf(o[7]) << 16);
        *(uint4*)(h1in_u + (size_t)node * 64 + t * 4) = res;
    }
}

__global__ __launch_bounds__(256) void k_agg1(
    const int* __restrict__ rowstart, const unsigned short* __restrict__ esrc,
    const __hip_bfloat16* __restrict__ h1,
    const float* __restrict__ a1s, const float* __restrict__ a1d,
    const float* __restrict__ bc1,                     // bias1+linb1 [32]
    float* __restrict__ out, int n) {
    int node = (blockIdx.x * 256 + threadIdx.x) >> 6;
    int lane = threadIdx.x & 63;
    if (node >= n) return;
    int g = lane >> 4, t = lane & 15;
    float ad = a1d[node];
    int s0 = rowstart[node], s1 = rowstart[node + 1];
    const unsigned int* h1w = (const unsigned int*)h1;  // row = 16 uints
    float den = 0.f, acc0 = 0.f, acc1 = 0.f;
    int i = s0 + g;
    for (; i + 12 < s1; i += 16) {             // 4 edges/group in flight
        int sE[4]; float e[4]; unsigned int p[4];
        #pragma unroll
        for (int j = 0; j < 4; j++) sE[j] = esrc[i + 4 * j];
        #pragma unroll
        for (int j = 0; j < 4; j++) e[j] = a1s[sE[j]] + ad;
        #pragma unroll
        for (int j = 0; j < 4; j++) p[j] = h1w[(size_t)sE[j] * 16 + t];
        #pragma unroll
        for (int j = 0; j < 4; j++) {
            float wgt = lrexp(e[j]);
            den += wgt;
            acc0 += wgt * blo(p[j]);
            acc1 += wgt * bhi(p[j]);
        }
    }
    for (; i < s1; i += 4) {
        int s = esrc[i];
        float wv = lrexp(a1s[s] + ad);
        unsigned int p = h1w[(size_t)s * 16 + t];
        den += wv; acc0 += wv * blo(p); acc1 += wv * bhi(p);
    }
    acc0 += __shfl_xor(acc0, 16); acc0 += __shfl_xor(acc0, 32);
    acc1 += __shfl_xor(acc1, 16); acc1 += __shfl_xor(acc1, 32);
    den  += __shfl_xor(den, 16);  den  += __shfl_xor(den, 32);
    if (g == 0) {
        float inv = 1.0f / (den + 1e-16f);
        int c0 = t * 2;
        size_t idx = (size_t)node * 32 + c0;
        float2 sk = *(const float2*)(out + idx);     // skip1
        float2 r;
        r.x = acc0 * inv + sk.x + bc1[c0];
        r.y = acc1 * inv + sk.y + bc1[c0 + 1];
        *(float2*)(out + idx) = r;
    }
}

// ---------------- launch ----------------

extern "C" void kernel_launch(void* const* d_in, const int* in_sizes, int n_in,
                              void* d_out, int out_size, void* d_ws, size_t ws_size,
                              hipStream_t stream) {
    const float* x   = (const float*)d_in[0];
    const int*   ei  = (const int*)d_in[1];
    const float* W0  = (const float*)d_in[2];
    const float* as0 = (const float*)d_in[3];
    const float* ad0 = (const float*)d_in[4];
    const float* b0  = (const float*)d_in[5];
    const float* lW0 = (const float*)d_in[6];
    const float* lb0 = (const float*)d_in[7];
    const float* W1  = (const float*)d_in[8];
    const float* as1 = (const float*)d_in[9];
    const float* ad1 = (const float*)d_in[10];
    const float* b1  = (const float*)d_in[11];
    const float* lW1 = (const float*)d_in[12];
    const float* lb1 = (const float*)d_in[13];
    float* out = (float*)d_out;

    const int N = in_sizes[0] / 128;
    const int E = in_sizes[1] / 2;
    const int T = E + N;
    const int NBK  = (N + 255) >> 8;        // used buckets (196)
    const int NBBK = (T + 2047) / 2048;     // bucket blocks (416)

    // workspace carve-up (256B aligned), ~38 MB
    char* w = (char*)d_ws;
    auto alloc = [&](size_t bytes) -> char* {
        char* p = w; w += (bytes + 255) / 256 * 256; return p;
    };
    int* rowstart  = (int*)alloc((size_t)(N + 1) * 4);
    int* gcur      = (int*)alloc(NBUCK * 4);
    unsigned int* bucketed = (unsigned int*)alloc((size_t)NBUCK * BCAP * 4);
    unsigned short* esrc = (unsigned short*)alloc((size_t)T * 2);
    float* aS      = (float*)alloc((size_t)N * 4 * 4);    // layer0 [N,4]; layer1 [N]
    float* aD      = (float*)alloc((size_t)N * 4 * 4);
    char* hbuf     = alloc((size_t)N * 128 * 2);          // h0 fp8 (N*128B) / h1 bf16
    __hip_bfloat16* h1in = (__hip_bfloat16*)alloc((size_t)N * 128 * 2); // skip0 -> ELU
    short* Wp0  = (short*)alloc(16384 * 2);
    short* lWp0 = (short*)alloc(16384 * 2);
    short* Wp1  = (short*)alloc(4096 * 2);
    short* lWp1 = (short*)alloc(4096 * 2);
    float* bc0  = (float*)alloc(128 * 4);
    float* bc1  = (float*)alloc(32 * 4);

    // L1: cursors; L2: weight-pack ∥ bucketing
    k_gz<<<1, NBUCK, 0, stream>>>(gcur);
    k_initbucket<<<64 + NBBK, 256, 0, stream>>>(ei, W0, lW0, W1, lW1,
                                                b0, lb0, b1, lb1,
                                                Wp0, lWp0, Wp1, lWp1, bc0, bc1,
                                                gcur, bucketed, E, T);
    // L3: CSR fill (self-scanned bases) ∥ gemm0(+att0, fp8 h0)
    k_fillgemm0<<<NBK + (N + 63) / 64, 256, 0, stream>>>(
        bucketed, gcur, rowstart, esrc,
        x, Wp0, lWp0, as0, ad0, (unsigned char*)hbuf, h1in, aS, aD, N);
    // L4-L6
    k_agg0<<<(N + 3) / 4, 256, 0, stream>>>(rowstart, esrc, (const uint2*)hbuf,
                                            aS, aD, bc0, (unsigned int*)h1in, N);
    k_gemm1<<<(N + 63) / 64, 256, 0, stream>>>(h1in, Wp1, lWp1, as1, ad1,
                                               (__hip_bfloat16*)hbuf, out, aS, aD, N);
    k_agg1<<<(N + 3) / 4, 256, 0, stream>>>(rowstart, esrc, (const __hip_bfloat16*)hbuf,
                                            aS, aD, bc1, out, N);
}